// Round 15
// baseline (64.759 us; speedup 1.0000x reference)
//
#include <hip/hip_runtime.h>
#include <hip/hip_bf16.h>
#include <math.h>

#define C1F  0.577078016f   // 0.4 * log2(e)
#define C2F  0.865617024f   // 0.6 * log2(e)

// ws byte offsets
#define WS_CNT 0                          // 16 x i64
#define WS_AGG 128                        // 1024 x i64  (ends 8320)
#define WS_G   8320                       // g[2048][64] f32 row-major (524288 B)
#define WS_DCL (8320 + 524288)            // dclT[4][2048] f32 (ends 573056)

typedef float __attribute__((ext_vector_type(4))) f32x4;

__device__ __forceinline__ float rfl(float x) {
    return __uint_as_float(__builtin_amdgcn_readfirstlane(__float_as_uint(x)));
}

// full wave64 sum via DPP (no DS pipe); total valid in lane 63.
__device__ __forceinline__ float dpp_sum(float x) {
    float y;
    y = __int_as_float(__builtin_amdgcn_update_dpp(0, __float_as_int(x), 0x111, 0xf, 0xf, true)); x += y;
    y = __int_as_float(__builtin_amdgcn_update_dpp(0, __float_as_int(x), 0x112, 0xf, 0xf, true)); x += y;
    y = __int_as_float(__builtin_amdgcn_update_dpp(0, __float_as_int(x), 0x114, 0xf, 0xf, true)); x += y;
    y = __int_as_float(__builtin_amdgcn_update_dpp(0, __float_as_int(x), 0x118, 0xf, 0xf, true)); x += y;
    y = __int_as_float(__builtin_amdgcn_update_dpp(0, __float_as_int(x), 0x142, 0xa, 0xf, true)); x += y;
    y = __int_as_float(__builtin_amdgcn_update_dpp(0, __float_as_int(x), 0x143, 0xc, 0xf, true)); x += y;
    return x;
}

// ---------------------------------------------------------------------------
// k_proj: ohm fill + g = pin @ Wl^T (row-major) + dclT[h][i] + label cnt
// ---------------------------------------------------------------------------
__global__ __launch_bounds__(256) void k_proj(
    const float* __restrict__ x, const float* __restrict__ ohm,
    const float* __restrict__ Wl, const float* __restrict__ Wattn,
    unsigned char* __restrict__ ws)
{
    float* g    = (float*)(ws + WS_G);
    float* dclT = (float*)(ws + WS_DCL);
    unsigned long long* cnt = (unsigned long long*)(ws + WS_CNT);

    int t = threadIdx.x;
    int r = blockIdx.x * 4 + (t >> 6);
    int o = t & 63;

    f32x4 oh[4]; float rs = 0.f;
    const f32x4* ohp = (const f32x4*)&ohm[r*16];
    #pragma unroll
    for (int q = 0; q < 4; ++q) { oh[q] = ohp[q]; rs += oh[q][0]+oh[q][1]+oh[q][2]+oh[q][3]; }
    if (rs == 0.f) {
        f32x4 c = {0.0625f, 0.0625f, 0.0625f, 0.0625f};
        #pragma unroll
        for (int q = 0; q < 4; ++q) oh[q] = c;
    }

    float acc = 0.f;
    const f32x4* xp = (const f32x4*)&x[r*64];
    const f32x4* wp = (const f32x4*)&Wl[o*80];
    #pragma unroll
    for (int q = 0; q < 16; ++q) {
        f32x4 a = xp[q], b = wp[q];
        acc = fmaf(a[0],b[0],acc); acc = fmaf(a[1],b[1],acc);
        acc = fmaf(a[2],b[2],acc); acc = fmaf(a[3],b[3],acc);
    }
    #pragma unroll
    for (int q = 0; q < 4; ++q) {
        f32x4 b = wp[16+q];
        acc = fmaf(oh[q][0],b[0],acc); acc = fmaf(oh[q][1],b[1],acc);
        acc = fmaf(oh[q][2],b[2],acc); acc = fmaf(oh[q][3],b[3],acc);
    }
    g[r*64 + o] = acc;

    float dot = Wattn[o & 15] * acc;
    #pragma unroll
    for (int m2 = 1; m2 < 16; m2 <<= 1) dot += __shfl_xor(dot, m2);
    if ((o & 15) == 0) dclT[(o >> 4)*2048 + r] = C2F * dot;   // transposed

    if (t < 16) {  // exact label counts, fixed-point 2^20 (ohm in {0,1,1/16})
        float c = 0.f;
        for (int rr = 0; rr < 4; ++rr) {
            int r2 = blockIdx.x*4 + rr; float s = 0.f;
            #pragma unroll
            for (int k = 0; k < 16; ++k) s += ohm[r2*16+k];
            c += (s == 0.f) ? 0.0625f : ohm[r2*16+t];
        }
        atomicAdd(&cnt[t], (unsigned long long)__float2ll_rn(c * 1048576.0f));
    }
}

// ---------------------------------------------------------------------------
// k_attn: flash attention. grid 512 x 256 (4 waves/block, 4 blocks/CU).
// wave = head h; all 4 block-rows' gA in SGPRs; thread = 2 j's per tile
// (j = l, 64+l). Single 34.8KB LDS buffer, r11-measured 0-conflict patterns,
// T14 order: write t -> sync -> issue loads t+1 -> compute t. Barrier stalls
// overlapped by 3 other co-resident blocks. DPP-only epilogue.
// ---------------------------------------------------------------------------
__global__ __launch_bounds__(256, 2) void k_attn(
    const float* __restrict__ ohm, const float* __restrict__ Wattn,
    unsigned char* __restrict__ ws, float* __restrict__ hout)
{
    float* g    = (float*)(ws + WS_G);
    float* dclT = (float*)(ws + WS_DCL);
    unsigned long long* agg = (unsigned long long*)(ws + WS_AGG);

    __shared__ float gl[128*68];     // 34,816 B single buffer
    __shared__ float shh[256];
    __shared__ float ohmf[64];

    int t = threadIdx.x, bid = blockIdx.x;
    int h = t >> 6, l = t & 63;
    int ib = bid*4;

    // staging: thread stages 8 f32x4 chunks v = t + q*256 (measured 0-conflict)
    const f32x4* gv4 = (const f32x4*)g;      // tile stride = 2048 f32x4
    float* wbase = &gl[(t >> 4)*68 + (t & 15)*4];

    // wave-uniform constants -> SGPRs
    float wv[16], gAs[4][16];
    #pragma unroll
    for (int f = 0; f < 16; ++f) wv[f] = rfl(Wattn[f]);
    #pragma unroll
    for (int r = 0; r < 4; ++r)
        #pragma unroll
        for (int f = 0; f < 16; ++f)
            gAs[r][f] = rfl(g[(ib + r)*64 + h*16 + f]);

    float acc[4][16];
    float ls[4] = {0.f, 0.f, 0.f, 0.f};
    #pragma unroll
    for (int r = 0; r < 4; ++r)
        #pragma unroll
        for (int f = 0; f < 16; ++f) acc[r][f] = 0.f;

    const float* dpt = dclT + h*2048 + l;    // dj(tile,k) = dpt[tile*128 + k*64]

    // prologue: tile 0 -> regs
    f32x4 st[8];
    #pragma unroll
    for (int q = 0; q < 8; ++q) st[q] = gv4[t + q*256];
    float djc0 = dpt[0], djc1 = dpt[64];
    float djn0 = 0.f, djn1 = 0.f;

    for (int tile = 0; tile < 16; ++tile) {
        if (tile) __syncthreads();           // readers of tile-1 done
        #pragma unroll
        for (int q = 0; q < 8; ++q) *(f32x4*)(wbase + q*1088) = st[q];  // 16*68
        __syncthreads();                     // writes visible
        if (tile < 15) {                     // issue next-tile loads early (T14)
            #pragma unroll
            for (int q = 0; q < 8; ++q) st[q] = gv4[(tile+1)*2048 + t + q*256];
            djn0 = dpt[(tile+1)*128];
            djn1 = dpt[(tile+1)*128 + 64];
        }

        // compute: j = {l, 64+l}; 4 i-rows amortized per LDS read
        #pragma unroll
        for (int k = 0; k < 2; ++k) {
            const float* gj = &gl[(k*64 + l)*68 + h*16];
            f32x4 q0 = *(const f32x4*)(gj);
            f32x4 q1 = *(const f32x4*)(gj+4);
            f32x4 q2 = *(const f32x4*)(gj+8);
            f32x4 q3 = *(const f32x4*)(gj+12);
            float gvv[16] = { q0[0],q0[1],q0[2],q0[3], q1[0],q1[1],q1[2],q1[3],
                              q2[0],q2[1],q2[2],q2[3], q3[0],q3[1],q3[2],q3[3] };
            float djk = k ? djc1 : djc0;
            float p[4];
            #pragma unroll
            for (int r = 0; r < 4; ++r) {
                float sa = 0.f, sb = 0.f;
                #pragma unroll
                for (int f = 0; f < 16; f += 2) {
                    float u0 = gAs[r][f]   + gvv[f];
                    float u1 = gAs[r][f+1] + gvv[f+1];
                    sa = fmaf(wv[f],   fabsf(u0), sa);   // |.| free VOP3 mod
                    sb = fmaf(wv[f+1], fabsf(u1), sb);
                }
                p[r] = __builtin_amdgcn_exp2f(fmaf(C1F, sa + sb, djk));
                ls[r] += p[r];
            }
            #pragma unroll
            for (int f = 0; f < 16; ++f) {
                acc[0][f] = fmaf(p[0], gvv[f], acc[0][f]);
                acc[1][f] = fmaf(p[1], gvv[f], acc[1][f]);
                acc[2][f] = fmaf(p[2], gvv[f], acc[2][f]);
                acc[3][f] = fmaf(p[3], gvv[f], acc[3][f]);
            }
        }
        djc0 = djn0; djc1 = djn1;
    }

    // full-wave DPP reduction -> lane 63; each (row,head) owned by ONE wave
    float lss[4], hv[4][16];
    #pragma unroll
    for (int r = 0; r < 4; ++r) {
        lss[r] = dpp_sum(ls[r]);
        #pragma unroll
        for (int f = 0; f < 16; ++f) hv[r][f] = dpp_sum(acc[r][f]);
    }

    if (l == 63) {
        #pragma unroll
        for (int r = 0; r < 4; ++r) {
            float rl = 1.0f / lss[r];
            #pragma unroll
            for (int f = 0; f < 16; ++f) {
                float a = hv[r][f]*rl; a = fmaxf(a, 0.2f*a);
                hout[(ib + r)*64 + h*16 + f] = a;
                shh[r*64 + h*16 + f] = a;
            }
        }
    }
    if (t < 64) {   // filled ohm for the block's 4 rows
        int rr = t >> 4, ll = t & 15;
        float v = ohm[(ib + rr)*16 + ll];
        float s = v;
        #pragma unroll
        for (int m2 = 1; m2 < 16; m2 <<= 1) s += __shfl_xor(s, m2);
        ohmf[rr*16 + ll] = (s == 0.f) ? 0.0625f : v;
    }
    __syncthreads();

    // deterministic centroid partial agg: int64 fixed-point 2^26 (order-free)
    for (int v = t; v < 1024; v += 256) {
        int ll = v >> 6, d = v & 63;
        float s = 0.f;
        #pragma unroll
        for (int rr = 0; rr < 4; ++rr) s = fmaf(ohmf[rr*16 + ll], shh[rr*64 + d], s);
        atomicAdd(&agg[v], (unsigned long long)__float2ll_rn(s * 67108864.0f));
    }
}

// ---------------------------------------------------------------------------
// k_scores: rebuild centroids per block from agg/cnt, then cdist.
// ---------------------------------------------------------------------------
__global__ __launch_bounds__(256) void k_scores(
    unsigned char* __restrict__ ws, const float* __restrict__ hout,
    float* __restrict__ scores, float* __restrict__ missing)
{
    __shared__ float cl[16*68];
    unsigned long long* cnt = (unsigned long long*)(ws + WS_CNT);
    unsigned long long* agg = (unsigned long long*)(ws + WS_AGG);
    int t = threadIdx.x;

    for (int v = t; v < 1024; v += 256) {
        int ll = v >> 6, d = v & 63;
        long long a = (long long)agg[v];
        long long c = (long long)cnt[ll];
        cl[ll*68 + d] = (c == 0) ? 0.f : ((float)a / (float)c) * 0.015625f;
    }
    if (blockIdx.x == 0 && t < 16) missing[t] = (cnt[t] == 0) ? 1.0f : 0.0f;
    __syncthreads();

    int i = blockIdx.x*16 + (t >> 4), ll = t & 15;
    float s = 0.f;
    #pragma unroll 16
    for (int d = 0; d < 64; ++d) {
        float diff = hout[i*64 + d] - cl[ll*68 + d];
        s = fmaf(diff, diff, s);
    }
    scores[i*16 + ll] = -sqrtf(s);
}

// ---------------------------------------------------------------------------
extern "C" void kernel_launch(void* const* d_in, const int* in_sizes, int n_in,
                              void* d_out, int out_size, void* d_ws, size_t ws_size,
                              hipStream_t stream)
{
    const float* x     = (const float*)d_in[0];
    const float* ohm   = (const float*)d_in[1];
    const float* Wl    = (const float*)d_in[2];
    const float* Wattn = (const float*)d_in[3];
    unsigned char* ws  = (unsigned char*)d_ws;

    float* out     = (float*)d_out;
    float* scores  = out;
    float* hout    = out + 2048*16;
    float* missing = out + 2048*16 + 2048*64;

    hipMemsetAsync(d_ws, 0, 8320, stream);           // cnt + agg
    k_proj  <<<512, 256, 0, stream>>>(x, ohm, Wl, Wattn, ws);
    k_attn  <<<512, 256, 0, stream>>>(ohm, Wattn, ws, hout);
    k_scores<<<128, 256, 0, stream>>>(ws, hout, scores, missing);
}

// Round 16
// 55.221 us; speedup vs baseline: 1.1727x; 1.1727x over previous
//
#include <hip/hip_runtime.h>
#include <hip/hip_bf16.h>
#include <math.h>

#define C1F  0.577078016f   // 0.4 * log2(e)
#define C2F  0.865617024f   // 0.6 * log2(e)

// ws byte offsets
#define WS_CNT 0                          // 16 x i64
#define WS_AGG 128                        // 1024 x i64  (ends 8320)
#define WS_G   8320                       // g2[4][16][2048] f32 (524288 B)
#define WS_DCL (8320 + 524288)            // dclT[4][2048] f32 (ends 573056)

typedef float __attribute__((ext_vector_type(4))) f32x4;

__device__ __forceinline__ float rfl(float x) {
    return __uint_as_float(__builtin_amdgcn_readfirstlane(__float_as_uint(x)));
}

// full wave64 sum via DPP (no DS pipe); total valid in lane 63.
__device__ __forceinline__ float dpp_sum(float x) {
    float y;
    y = __int_as_float(__builtin_amdgcn_update_dpp(0, __float_as_int(x), 0x111, 0xf, 0xf, true)); x += y;
    y = __int_as_float(__builtin_amdgcn_update_dpp(0, __float_as_int(x), 0x112, 0xf, 0xf, true)); x += y;
    y = __int_as_float(__builtin_amdgcn_update_dpp(0, __float_as_int(x), 0x114, 0xf, 0xf, true)); x += y;
    y = __int_as_float(__builtin_amdgcn_update_dpp(0, __float_as_int(x), 0x118, 0xf, 0xf, true)); x += y;
    y = __int_as_float(__builtin_amdgcn_update_dpp(0, __float_as_int(x), 0x142, 0xa, 0xf, true)); x += y;
    y = __int_as_float(__builtin_amdgcn_update_dpp(0, __float_as_int(x), 0x143, 0xc, 0xf, true)); x += y;
    return x;
}

// ---------------------------------------------------------------------------
// k_proj: ohm fill + g2[h][f][j] = (pin @ Wl^T)^T + dclT[h][i] + label cnt
// ---------------------------------------------------------------------------
__global__ __launch_bounds__(256) void k_proj(
    const float* __restrict__ x, const float* __restrict__ ohm,
    const float* __restrict__ Wl, const float* __restrict__ Wattn,
    unsigned char* __restrict__ ws)
{
    float* g2   = (float*)(ws + WS_G);
    float* dclT = (float*)(ws + WS_DCL);
    unsigned long long* cnt = (unsigned long long*)(ws + WS_CNT);

    int t = threadIdx.x;
    int r = blockIdx.x * 4 + (t >> 6);
    int o = t & 63;

    f32x4 oh[4]; float rs = 0.f;
    const f32x4* ohp = (const f32x4*)&ohm[r*16];
    #pragma unroll
    for (int q = 0; q < 4; ++q) { oh[q] = ohp[q]; rs += oh[q][0]+oh[q][1]+oh[q][2]+oh[q][3]; }
    if (rs == 0.f) {
        f32x4 c = {0.0625f, 0.0625f, 0.0625f, 0.0625f};
        #pragma unroll
        for (int q = 0; q < 4; ++q) oh[q] = c;
    }

    float acc = 0.f;
    const f32x4* xp = (const f32x4*)&x[r*64];
    const f32x4* wp = (const f32x4*)&Wl[o*80];
    #pragma unroll
    for (int q = 0; q < 16; ++q) {
        f32x4 a = xp[q], b = wp[q];
        acc = fmaf(a[0],b[0],acc); acc = fmaf(a[1],b[1],acc);
        acc = fmaf(a[2],b[2],acc); acc = fmaf(a[3],b[3],acc);
    }
    #pragma unroll
    for (int q = 0; q < 4; ++q) {
        f32x4 b = wp[16+q];
        acc = fmaf(oh[q][0],b[0],acc); acc = fmaf(oh[q][1],b[1],acc);
        acc = fmaf(oh[q][2],b[2],acc); acc = fmaf(oh[q][3],b[3],acc);
    }
    // transposed store: g2[h][f][j]
    g2[(o >> 4)*32768 + (o & 15)*2048 + r] = acc;

    float dot = Wattn[o & 15] * acc;
    #pragma unroll
    for (int m2 = 1; m2 < 16; m2 <<= 1) dot += __shfl_xor(dot, m2);
    if ((o & 15) == 0) dclT[(o >> 4)*2048 + r] = C2F * dot;

    if (t < 16) {  // exact label counts, fixed-point 2^20 (ohm in {0,1,1/16})
        float c = 0.f;
        for (int rr = 0; rr < 4; ++rr) {
            int r2 = blockIdx.x*4 + rr; float s = 0.f;
            #pragma unroll
            for (int k = 0; k < 16; ++k) s += ohm[r2*16+k];
            c += (s == 0.f) ? 0.0625f : ohm[r2*16+t];
        }
        atomicAdd(&cnt[t], (unsigned long long)__float2ll_rn(c * 1048576.0f));
    }
}

// ---------------------------------------------------------------------------
// k_attn: whole-head LDS residency, zero main-loop barriers. grid 256 x 1024.
// block = (head h = bid>>6, 32 rows). Stage g2[h] (128KB) + dclT[h] (8KB)
// into LDS once; then 16 free-running waves (wave = 2 rows, gA in SGPR;
// thread = 4 j per pass, 8 passes). All G reads are stride-1 ds_read_b128
// (0-conflict); G re-reads (if compiler drops regs) cost ~12cyc, not L2 ~200.
// ---------------------------------------------------------------------------
__global__ __launch_bounds__(1024, 1) void k_attn(
    const float* __restrict__ ohm, const float* __restrict__ Wattn,
    unsigned char* __restrict__ ws, float* __restrict__ hout)
{
    float* g2   = (float*)(ws + WS_G);
    float* dclT = (float*)(ws + WS_DCL);
    unsigned long long* agg = (unsigned long long*)(ws + WS_AGG);

    __shared__ float g2l[16*2048];   // 131,072 B  (f-major, stride-1 in j)
    __shared__ float djl[2048];      //   8,192 B
    __shared__ float shh[32*16];     //   2,048 B
    __shared__ float ohmf[32*16];    //   2,048 B  -> 143,360 B total

    int t = threadIdx.x, bid = blockIdx.x;
    int h  = bid >> 6;           // 4 heads x 64 row-groups
    int ib = (bid & 63) * 32;    // first of 32 rows
    int wid = t >> 6, l = t & 63;
    int i0 = ib + wid*2, i1 = i0 + 1;

    const float* g2h = g2 + h*32768;
    const float* dph = dclT + h*2048;

    // ---- stage whole head into LDS (coalesced), plus SGPR constants ----
    {
        const f32x4* s4 = (const f32x4*)g2h;
        f32x4* d4 = (f32x4*)g2l;
        #pragma unroll
        for (int c = 0; c < 8; ++c) d4[t + c*1024] = s4[t + c*1024];
        if (t < 512) ((f32x4*)djl)[t] = ((const f32x4*)dph)[t];
    }
    float wv[16], gA0[16], gA1[16];
    #pragma unroll
    for (int f = 0; f < 16; ++f) {
        wv[f]  = rfl(Wattn[f]);
        gA0[f] = rfl(g2h[f*2048 + i0]);
        gA1[f] = rfl(g2h[f*2048 + i1]);
    }
    __syncthreads();   // the only pre-epilogue barrier

    float acc0[16], acc1[16];
    float l0 = 0.f, l1 = 0.f;
    #pragma unroll
    for (int f = 0; f < 16; ++f) { acc0[f] = 0.f; acc1[f] = 0.f; }

    for (int pass = 0; pass < 8; ++pass) {
        int jb = pass*256 + 4*l;
        f32x4 G[16];
        #pragma unroll
        for (int f = 0; f < 16; ++f) G[f] = *(const f32x4*)&g2l[f*2048 + jb];
        f32x4 dj = *(const f32x4*)&djl[jb];

        float e00=0.f,e01=0.f,e02=0.f,e03=0.f;
        float e10=0.f,e11=0.f,e12=0.f,e13=0.f;
        #pragma unroll
        for (int f = 0; f < 16; ++f) {
            float a0 = gA0[f], a1 = gA1[f];
            f32x4 gf = G[f];
            e00 = fmaf(wv[f], fabsf(a0 + gf[0]), e00);   // |.| = free VOP3 mod
            e01 = fmaf(wv[f], fabsf(a0 + gf[1]), e01);
            e02 = fmaf(wv[f], fabsf(a0 + gf[2]), e02);
            e03 = fmaf(wv[f], fabsf(a0 + gf[3]), e03);
            e10 = fmaf(wv[f], fabsf(a1 + gf[0]), e10);
            e11 = fmaf(wv[f], fabsf(a1 + gf[1]), e11);
            e12 = fmaf(wv[f], fabsf(a1 + gf[2]), e12);
            e13 = fmaf(wv[f], fabsf(a1 + gf[3]), e13);
        }
        float p00 = __builtin_amdgcn_exp2f(fmaf(C1F, e00, dj[0]));
        float p01 = __builtin_amdgcn_exp2f(fmaf(C1F, e01, dj[1]));
        float p02 = __builtin_amdgcn_exp2f(fmaf(C1F, e02, dj[2]));
        float p03 = __builtin_amdgcn_exp2f(fmaf(C1F, e03, dj[3]));
        float p10 = __builtin_amdgcn_exp2f(fmaf(C1F, e10, dj[0]));
        float p11 = __builtin_amdgcn_exp2f(fmaf(C1F, e11, dj[1]));
        float p12 = __builtin_amdgcn_exp2f(fmaf(C1F, e12, dj[2]));
        float p13 = __builtin_amdgcn_exp2f(fmaf(C1F, e13, dj[3]));
        l0 += (p00 + p01) + (p02 + p03);
        l1 += (p10 + p11) + (p12 + p13);
        #pragma unroll
        for (int f = 0; f < 16; ++f) {
            f32x4 gf = G[f];
            acc0[f] = fmaf(p00, gf[0], fmaf(p01, gf[1],
                      fmaf(p02, gf[2], fmaf(p03, gf[3], acc0[f]))));
            acc1[f] = fmaf(p10, gf[0], fmaf(p11, gf[1],
                      fmaf(p12, gf[2], fmaf(p13, gf[3], acc1[f]))));
        }
    }

    // full-wave DPP reduction -> lane 63; each (row,head) owned by ONE wave
    float ls0 = dpp_sum(l0), ls1 = dpp_sum(l1);
    float h0[16], h1[16];
    #pragma unroll
    for (int f = 0; f < 16; ++f) { h0[f] = dpp_sum(acc0[f]); h1[f] = dpp_sum(acc1[f]); }

    if (l == 63) {
        float r0 = 1.0f / ls0, r1 = 1.0f / ls1;
        #pragma unroll
        for (int f = 0; f < 16; ++f) {
            float a = h0[f]*r0; a = fmaxf(a, 0.2f*a);
            float b = h1[f]*r1; b = fmaxf(b, 0.2f*b);
            hout[i0*64 + h*16 + f] = a;
            hout[i1*64 + h*16 + f] = b;
            shh[(wid*2    )*16 + f] = a;
            shh[(wid*2 + 1)*16 + f] = b;
        }
    }
    if (t < 512) {   // filled ohm for the block's 32 rows
        int r = t >> 4, lab = t & 15;
        float v = ohm[(ib + r)*16 + lab];
        float s = v;
        #pragma unroll
        for (int m2 = 1; m2 < 16; m2 <<= 1) s += __shfl_xor(s, m2);
        ohmf[r*16 + lab] = (s == 0.f) ? 0.0625f : v;
    }
    __syncthreads();

    // deterministic centroid partial agg for this block's (32 rows, 16 dims)
    if (t < 256) {
        int lab = t >> 4, dq = t & 15;
        float s = 0.f;
        #pragma unroll 8
        for (int r = 0; r < 32; ++r)
            s = fmaf(ohmf[r*16 + lab], shh[r*16 + dq], s);
        atomicAdd(&agg[lab*64 + h*16 + dq],
                  (unsigned long long)__float2ll_rn(s * 67108864.0f));
    }
}

// ---------------------------------------------------------------------------
// k_scores: rebuild centroids per block from agg/cnt, then cdist.
// ---------------------------------------------------------------------------
__global__ __launch_bounds__(256) void k_scores(
    unsigned char* __restrict__ ws, const float* __restrict__ hout,
    float* __restrict__ scores, float* __restrict__ missing)
{
    __shared__ float cl[16*68];
    unsigned long long* cnt = (unsigned long long*)(ws + WS_CNT);
    unsigned long long* agg = (unsigned long long*)(ws + WS_AGG);
    int t = threadIdx.x;

    for (int v = t; v < 1024; v += 256) {
        int ll = v >> 6, d = v & 63;
        long long a = (long long)agg[v];
        long long c = (long long)cnt[ll];
        cl[ll*68 + d] = (c == 0) ? 0.f : ((float)a / (float)c) * 0.015625f;
    }
    if (blockIdx.x == 0 && t < 16) missing[t] = (cnt[t] == 0) ? 1.0f : 0.0f;
    __syncthreads();

    int i = blockIdx.x*16 + (t >> 4), ll = t & 15;
    float s = 0.f;
    #pragma unroll 16
    for (int d = 0; d < 64; ++d) {
        float diff = hout[i*64 + d] - cl[ll*68 + d];
        s = fmaf(diff, diff, s);
    }
    scores[i*16 + ll] = -sqrtf(s);
}

// ---------------------------------------------------------------------------
extern "C" void kernel_launch(void* const* d_in, const int* in_sizes, int n_in,
                              void* d_out, int out_size, void* d_ws, size_t ws_size,
                              hipStream_t stream)
{
    const float* x     = (const float*)d_in[0];
    const float* ohm   = (const float*)d_in[1];
    const float* Wl    = (const float*)d_in[2];
    const float* Wattn = (const float*)d_in[3];
    unsigned char* ws  = (unsigned char*)d_ws;

    float* out     = (float*)d_out;
    float* scores  = out;
    float* hout    = out + 2048*16;
    float* missing = out + 2048*16 + 2048*64;

    hipMemsetAsync(d_ws, 0, 8320, stream);           // cnt + agg
    k_proj  <<<512, 256, 0, stream>>>(x, ohm, Wl, Wattn, ws);
    k_attn  <<<256, 1024, 0, stream>>>(ohm, Wattn, ws, hout);
    k_scores<<<128, 256, 0, stream>>>(ws, hout, scores, missing);
}